// Round 1
// baseline (2449.062 us; speedup 1.0000x reference)
//
#include <hip/hip_runtime.h>
#include <hip/hip_bf16.h>
#include <cstdint>

// ---------------------------------------------------------------------------
// RNN_CRF: BiLSTM(B=32,T=256,E=256,H=512) -> linear(K=32) -> CRF viterbi
// ---------------------------------------------------------------------------

typedef __attribute__((ext_vector_type(8)))  short          s8v;
typedef __attribute__((ext_vector_type(8)))  __bf16         bf8v;
typedef __attribute__((ext_vector_type(16))) float          f32x16;
typedef __attribute__((ext_vector_type(4)))  float          f32x4v;
typedef __attribute__((ext_vector_type(4)))  unsigned int   u32x4;
typedef __attribute__((ext_vector_type(8)))  unsigned short u16x8;
typedef __attribute__((ext_vector_type(4)))  unsigned short u16x4;

// ---- mfma shim: gfx950 builtin may take v8bf16 or v8i16 -------------------
template <typename V>
static __device__ inline auto mfma_try(V a, V b, f32x16 c, int)
    -> decltype(__builtin_amdgcn_mfma_f32_32x32x16_bf16(a, b, c, 0, 0, 0)) {
  return __builtin_amdgcn_mfma_f32_32x32x16_bf16(a, b, c, 0, 0, 0);
}
template <typename V>
static __device__ inline f32x16 mfma_try(V a, V b, f32x16 c, long) {
  return __builtin_amdgcn_mfma_f32_32x32x16_bf16(
      __builtin_bit_cast(bf8v, a), __builtin_bit_cast(bf8v, b), c, 0, 0, 0);
}
static __device__ inline f32x16 mfma32(u16x8 a, u16x8 b, f32x16 c) {
  return mfma_try(__builtin_bit_cast(s8v, a), __builtin_bit_cast(s8v, b), c, 0);
}

// ---- bf16 split helpers (truncation split: x ~= hi + lo, err <= 2^-17|x|) -
static __device__ inline unsigned short bf_trunc(float x) {
  return (unsigned short)(__builtin_bit_cast(unsigned int, x) >> 16);
}
static __device__ inline float bf_up(unsigned short h) {
  return __builtin_bit_cast(float, ((unsigned int)h) << 16);
}
static __device__ inline void split2(float x, unsigned short& hi, unsigned short& lo) {
  hi = bf_trunc(x);
  lo = bf_trunc(x - bf_up(hi));
}
static __device__ inline float sigmoidf_(float x) { return 1.0f / (1.0f + __expf(-x)); }
static __device__ inline float tanhf_(float x) {
  float ax = fabsf(x);
  float e  = __expf(-2.0f * ax);
  float t  = (1.0f - e) / (1.0f + e);
  return x < 0.0f ? -t : t;
}

// ---- coherent (LLC-direct) 16B load ---------------------------------------
static __device__ inline u32x4 ld_cohere16(const void* p) {
  u32x4 r;
  asm volatile("global_load_dwordx4 %0, %1, off sc0 sc1" : "=v"(r) : "v"(p) : "memory");
  return r;
}
static __device__ inline void wait_vm0() {
  asm volatile("s_waitcnt vmcnt(0)" ::: "memory");
  __builtin_amdgcn_sched_barrier(0);  // rule #18: keep MFMAs below the wait
}

// ===========================================================================
// K1: embedding gather -> x split to bf16 hi/lo. row = t*32+b, 256 elems.
// ===========================================================================
__global__ void k_embed(const int* __restrict__ sent, const float* __restrict__ emb,
                        unsigned short* __restrict__ xhi, unsigned short* __restrict__ xlo) {
  int row  = blockIdx.x * 4 + (threadIdx.x >> 6);
  int lane = threadIdx.x & 63;
  int t = row >> 5, b = row & 31;
  int tok = sent[b * 256 + t];
  const f32x4v v = *(const f32x4v*)(emb + (long)tok * 256 + lane * 4);
  u16x4 h4, l4;
#pragma unroll
  for (int i = 0; i < 4; ++i) {
    unsigned short h, l;
    split2(v[i], h, l);
    h4[i] = h; l4[i] = l;
  }
  *(u16x4*)(xhi + (long)row * 256 + lane * 4) = h4;
  *(u16x4*)(xlo + (long)row * 256 + lane * 4) = l4;
}

// ===========================================================================
// K3: persistent bidirectional LSTM.
// 128 blocks: dir = blk>>6, b64 = blk&63. Block owns h-indices [b64*8, b64*8+8)
// i.e. 32 rows of W_hh/W_ih ({g*512 + i}), preloaded as bf16 hi/lo MFMA B-frags
// in registers. Per step: z = x_t @ Wih^T + h @ Whh^T via 32x32x16 bf16x3 MFMA
// (4 waves split K), LDS partial reduction, gate math on 256 threads
// (thread j: b=j&31, il=j>>5), h published as hi/lo bf16 + release flag.
// ===========================================================================
__global__ __launch_bounds__(256, 1) void k_lstm(
    const float* __restrict__ Whh_f, const float* __restrict__ Whh_b,
    const float* __restrict__ Wih_f, const float* __restrict__ Wih_b,
    const float* __restrict__ b_f,   const float* __restrict__ b_b,
    const float* __restrict__ h0,    const float* __restrict__ c0,
    const unsigned short* __restrict__ xhi, const unsigned short* __restrict__ xlo,
    unsigned short* __restrict__ hbhi, unsigned short* __restrict__ hblo,
    unsigned short* __restrict__ hshi, unsigned short* __restrict__ hslo,
    int* __restrict__ flags) {
  const int tid = threadIdx.x, lane = tid & 63, w = tid >> 6;
  const int blk = blockIdx.x, dir = blk >> 6, b64 = blk & 63;
  const float* Whh  = dir ? Whh_b : Whh_f;
  const float* Wih  = dir ? Wih_b : Wih_f;
  const float* bias = dir ? b_b   : b_f;

  __shared__ float zp[4][32][33];

  const int n  = lane & 31;   // B-frag col == our row-list index
  const int kh = lane >> 5;   // k half within 16-wide K step
  const int wrow = ((n >> 3) << 9) + (b64 << 3) + (n & 7);  // W row (gate*512 + idx)

  // ---- preload recurrent B-frags (K=512, wave w covers [w*128, w*128+128))
  u16x8 wbh[8], wbl[8];
#pragma unroll
  for (int k8 = 0; k8 < 8; ++k8) {
    const float* src = Whh + (long)wrow * 512 + (w << 7) + (k8 << 4) + (kh << 3);
    f32x4v a = *(const f32x4v*)src, b2 = *(const f32x4v*)(src + 4);
    u16x8 hh, ll;
#pragma unroll
    for (int i = 0; i < 8; ++i) {
      float v = (i < 4) ? a[i] : b2[i - 4];
      unsigned short x1, x2; split2(v, x1, x2);
      hh[i] = x1; ll[i] = x2;
    }
    wbh[k8] = hh; wbl[k8] = ll;
  }
  // ---- preload input-proj B-frags (K=256, wave w covers [w*64, w*64+64))
  u16x8 wih_h[4], wih_l[4];
#pragma unroll
  for (int k4 = 0; k4 < 4; ++k4) {
    const float* src = Wih + (long)wrow * 256 + (w << 6) + (k4 << 4) + (kh << 3);
    f32x4v a = *(const f32x4v*)src, b2 = *(const f32x4v*)(src + 4);
    u16x8 hh, ll;
#pragma unroll
    for (int i = 0; i < 8; ++i) {
      float v = (i < 4) ? a[i] : b2[i - 4];
      unsigned short x1, x2; split2(v, x1, x2);
      hh[i] = x1; ll[i] = x2;
    }
    wih_h[k4] = hh; wih_l[k4] = ll;
  }

  // ---- gate-thread state
  const int gb = tid & 31;          // batch
  const int gi = tid >> 5;          // local h index 0..7
  const int gidx = (b64 << 3) + gi; // global h index
  float c = c0[(dir * 32 + gb) * 512 + gidx];
  float bias4[4];
#pragma unroll
  for (int g = 0; g < 4; ++g) bias4[g] = bias[(g << 9) + gidx];

  // ---- publish h_0 (parity 0)
  {
    float hv = h0[(dir * 32 + gb) * 512 + gidx];
    unsigned short hh, ll; split2(hv, hh, ll);
    int off = ((0 * 2 + dir) * 64 + b64) * 256 + gb * 8 + gi;
    hbhi[off] = hh; hblo[off] = ll;
  }
  __syncthreads();  // drains vmcnt/lgkmcnt for all threads
  if (tid == 0)
    __hip_atomic_store(&flags[dir * 64 + b64], 1, __ATOMIC_RELEASE, __HIP_MEMORY_SCOPE_AGENT);

  const int m = lane & 31;  // A-frag row == batch

  for (int step = 0; step < 256; ++step) {
    const int t = dir ? (255 - step) : step;

    // x A-frags (plain cached loads; no dependence on flags)
    u16x8 xah[4], xal[4];
#pragma unroll
    for (int k4 = 0; k4 < 4; ++k4) {
      long ro = (long)(t * 32 + m) * 256 + (w << 6) + (k4 << 4) + (kh << 3);
      xah[k4] = *(const u16x8*)(xhi + ro);
      xal[k4] = *(const u16x8*)(xlo + ro);
    }

    // wait for all 64 producer blocks of this direction to finish round `step`
    {
      const int* fl = flags + dir * 64;
      const int tgt = step + 1;
      while (true) {
        int fv = __hip_atomic_load(fl + lane, __ATOMIC_RELAXED, __HIP_MEMORY_SCOPE_AGENT);
        if (__all(fv >= tgt)) break;
      }
    }

    // h A-frags: coherent loads from hbuf parity (step&1)
    const int pr = step & 1;
    const unsigned short* hb_hi = hbhi + ((pr * 2 + dir) * 64) * 256;
    const unsigned short* hb_lo = hblo + ((pr * 2 + dir) * 64) * 256;
    u32x4 ah_[8], al_[8];
#pragma unroll
    for (int k8 = 0; k8 < 8; ++k8) {
      int ksrc = (w << 7) + (k8 << 4) + (kh << 3);
      int bs = ksrc >> 3;  // producer block holding these 8 h-indices
      ah_[k8] = ld_cohere16(hb_hi + bs * 256 + m * 8);
      al_[k8] = ld_cohere16(hb_lo + bs * 256 + m * 8);
    }

    f32x16 acc = (f32x16)0.0f;
    // input projection (overlaps h-load latency)
#pragma unroll
    for (int k4 = 0; k4 < 4; ++k4) {
      acc = mfma32(xah[k4], wih_h[k4], acc);
      acc = mfma32(xah[k4], wih_l[k4], acc);
      acc = mfma32(xal[k4], wih_h[k4], acc);
    }
    wait_vm0();
    // recurrent part (bf16x3)
#pragma unroll
    for (int k8 = 0; k8 < 8; ++k8) {
      u16x8 ah = __builtin_bit_cast(u16x8, ah_[k8]);
      u16x8 al = __builtin_bit_cast(u16x8, al_[k8]);
      acc = mfma32(ah, wbh[k8], acc);
      acc = mfma32(ah, wbl[k8], acc);
      acc = mfma32(al, wbh[k8], acc);
    }

    // partial z to LDS: C row = (reg&3)+8*(reg>>2)+4*kh (batch), col = n
#pragma unroll
    for (int r = 0; r < 16; ++r) {
      int mr = (r & 3) + ((r >> 2) << 3) + (kh << 2);
      zp[w][mr][n] = acc[r];
    }
    __syncthreads();

    // gate math
    float z[4];
#pragma unroll
    for (int g = 0; g < 4; ++g)
      z[g] = zp[0][gb][g * 8 + gi] + zp[1][gb][g * 8 + gi] +
             zp[2][gb][g * 8 + gi] + zp[3][gb][g * 8 + gi] + bias4[g];
    float ig = sigmoidf_(z[0]);
    float fg = sigmoidf_(z[1]);
    float gg = tanhf_(z[2]);
    float og = sigmoidf_(z[3]);
    c = fg * c + ig * gg;
    float nh = og * tanhf_(c);

    unsigned short hh, ll; split2(nh, hh, ll);
    const int pw = (step + 1) & 1;
    int off = ((pw * 2 + dir) * 64 + b64) * 256 + gb * 8 + gi;
    hbhi[off] = hh; hblo[off] = ll;
    long ho = ((long)(dir * 256 + t) * 64 + b64) * 256 + gb * 8 + gi;
    hshi[ho] = hh; hslo[ho] = ll;

    __syncthreads();  // all block stores drained to L2 before release
    if (tid == 0)
      __hip_atomic_store(&flags[dir * 64 + b64], step + 2, __ATOMIC_RELEASE,
                         __HIP_MEMORY_SCOPE_AGENT);
  }
}

// ===========================================================================
// K4: feats[b,t,k] = concat(hf,hb) @ Wout^T + bout. One block per t.
// Same bf16x3 MFMA pattern; wave w: dir = w>>1, K-half = (w&1)*256.
// ===========================================================================
__global__ __launch_bounds__(256, 1) void k_feats(
    const unsigned short* __restrict__ hshi, const unsigned short* __restrict__ hslo,
    const float* __restrict__ Wout, const float* __restrict__ bout,
    float* __restrict__ feats) {
  const int tid = threadIdx.x, lane = tid & 63, w = tid >> 6;
  const int t = blockIdx.x;
  __shared__ float zp[4][32][33];
  const int n = lane & 31, kh = lane >> 5;
  const int dirw = w >> 1, koff = (w & 1) * 256;

  u16x8 bh[16], bl[16];
#pragma unroll
  for (int k = 0; k < 16; ++k) {
    const float* src = Wout + (long)n * 1024 + dirw * 512 + koff + (k << 4) + (kh << 3);
    f32x4v a = *(const f32x4v*)src, b2 = *(const f32x4v*)(src + 4);
    u16x8 hh, ll;
#pragma unroll
    for (int i = 0; i < 8; ++i) {
      float v = (i < 4) ? a[i] : b2[i - 4];
      unsigned short x1, x2; split2(v, x1, x2);
      hh[i] = x1; ll[i] = x2;
    }
    bh[k] = hh; bl[k] = ll;
  }

  const int m = lane & 31;  // batch
  f32x16 acc = (f32x16)0.0f;
  const unsigned short* base_h = hshi + ((long)(dirw * 256 + t) * 64) * 256;
  const unsigned short* base_l = hslo + ((long)(dirw * 256 + t) * 64) * 256;
#pragma unroll
  for (int k = 0; k < 16; ++k) {
    int ksrc = koff + (k << 4) + (kh << 3);
    int bs = ksrc >> 3;
    u16x8 ah = *(const u16x8*)(base_h + bs * 256 + m * 8);
    u16x8 al = *(const u16x8*)(base_l + bs * 256 + m * 8);
    acc = mfma32(ah, bh[k], acc);
    acc = mfma32(ah, bl[k], acc);
    acc = mfma32(al, bh[k], acc);
  }
#pragma unroll
  for (int r = 0; r < 16; ++r) {
    int mr = (r & 3) + ((r >> 2) << 3) + (kh << 2);
    zp[w][mr][n] = acc[r];
  }
  __syncthreads();

  const int k = tid & 31, mb = tid >> 5;
#pragma unroll
  for (int q = 0; q < 4; ++q) {
    int mm = mb * 4 + q;  // batch
    float v = zp[0][mm][k] + zp[1][mm][k] + zp[2][mm][k] + zp[3][mm][k] + bout[k];
    feats[((long)mm * 256 + t) * 32 + k] = v;
  }
}

// ===========================================================================
// K5: Viterbi decode. One 64-thread block per batch. Exact f32 semantics,
// first-index tie-break (matches jnp.argmax). bp kept in LDS.
// ===========================================================================
__global__ void k_viterbi(const float* __restrict__ feats, const float* __restrict__ trans,
                          float* __restrict__ out) {
  const int b = blockIdx.x;
  const int lane = threadIdx.x;
  __shared__ float tr[32][33];
  __shared__ float vl[33];
  __shared__ unsigned char bp[256][32];

  for (int i = lane; i < 1024; i += 64) tr[i >> 5][i & 31] = trans[i];
  if (lane < 32) vl[lane] = (lane == 30) ? 0.0f : -10000.0f;
  __syncthreads();

  const int nxt = lane >> 1, half = lane & 1;
  for (int t = 0; t < 256; ++t) {
    float f = feats[((long)b * 256 + t) * 32 + nxt];
    float best = -3.0e38f; int arg = 0;
    const int p0 = half * 16;
#pragma unroll
    for (int pp = 0; pp < 16; ++pp) {
      int p = p0 + pp;
      float sc = vl[p] + tr[nxt][p];
      if (sc > best) { best = sc; arg = p; }
    }
    float ob = __shfl_xor(best, 1);
    int   oa = __shfl_xor(arg, 1);
    if (ob > best || (ob == best && oa < arg)) { best = ob; arg = oa; }
    __syncthreads();
    if (half == 0) {
      vl[nxt] = best + f;
      bp[t][nxt] = (unsigned char)arg;
    }
    __syncthreads();
  }

  // terminal = v + trans[STOP=31][:]
  float tv = (lane < 32) ? (vl[lane] + tr[31][lane]) : -3.4e38f;
  int ta = lane;
#pragma unroll
  for (int d = 32; d; d >>= 1) {
    float ov = __shfl_xor(tv, d);
    int   oa = __shfl_xor(ta, d);
    if (ov > tv || (ov == tv && oa < ta)) { tv = ov; ta = oa; }
  }
  if (lane == 0) {
    out[b] = tv;
    int tag = ta;
    for (int t = 255; t >= 0; --t) {
      out[32 + (long)b * 256 + t] = (float)tag;
      tag = bp[t][tag];
    }
  }
}

// ===========================================================================
extern "C" void kernel_launch(void* const* d_in, const int* in_sizes, int n_in,
                              void* d_out, int out_size, void* d_ws, size_t ws_size,
                              hipStream_t stream) {
  (void)in_sizes; (void)n_in; (void)out_size; (void)ws_size;
  const int*   sent  = (const int*)d_in[0];
  const float* emb   = (const float*)d_in[1];
  const float* Wih_f = (const float*)d_in[2];
  const float* Whh_f = (const float*)d_in[3];
  const float* b_f   = (const float*)d_in[4];
  const float* Wih_b = (const float*)d_in[5];
  const float* Whh_b = (const float*)d_in[6];
  const float* b_b   = (const float*)d_in[7];
  const float* Wout  = (const float*)d_in[8];
  const float* bout  = (const float*)d_in[9];
  const float* trans = (const float*)d_in[10];
  const float* h0    = (const float*)d_in[11];
  const float* c0    = (const float*)d_in[12];
  float* out = (float*)d_out;

  char* ws = (char*)d_ws;
  unsigned short* xhi  = (unsigned short*)(ws + 0);                       // 4 MB
  unsigned short* xlo  = (unsigned short*)(ws + (4ull << 20));            // 4 MB
  unsigned short* hbhi = (unsigned short*)(ws + (8ull << 20));            // 128 KB
  unsigned short* hblo = (unsigned short*)(ws + (8ull << 20) + (256ull << 10));
  unsigned short* hshi = (unsigned short*)(ws + (9ull << 20));            // 16 MB
  unsigned short* hslo = (unsigned short*)(ws + (26ull << 20));           // 16 MB
  float*          fts  = (float*)(ws + (43ull << 20));                    // 1 MB
  int*            flg  = (int*)(ws + (45ull << 20));                      // 512 B

  hipMemsetAsync(flg, 0, 128 * sizeof(int), stream);
  k_embed<<<2048, 256, 0, stream>>>(sent, emb, xhi, xlo);
  k_lstm<<<128, 256, 0, stream>>>(Whh_f, Whh_b, Wih_f, Wih_b, b_f, b_b, h0, c0,
                                  xhi, xlo, hbhi, hblo, hshi, hslo, flg);
  k_feats<<<256, 256, 0, stream>>>(hshi, hslo, Wout, bout, fts);
  k_viterbi<<<32, 64, 0, stream>>>(fts, trans, out);
}

// Round 3
// 1260.468 us; speedup vs baseline: 1.9430x; 1.9430x over previous
//
#include <hip/hip_runtime.h>
#include <hip/hip_bf16.h>
#include <cstdint>

// ---------------------------------------------------------------------------
// RNN_CRF: BiLSTM(B=32,T=256,E=256,H=512) -> linear(K=32) -> CRF viterbi
// Persistent flag-synced LSTM; hand-rolled release/acquire (no buffer_wbl2).
// ---------------------------------------------------------------------------

typedef __attribute__((ext_vector_type(8)))  short          s8v;
typedef __attribute__((ext_vector_type(8)))  __bf16         bf8v;
typedef __attribute__((ext_vector_type(16))) float          f32x16;
typedef __attribute__((ext_vector_type(4)))  float          f32x4v;
typedef __attribute__((ext_vector_type(4)))  unsigned int   u32x4;
typedef __attribute__((ext_vector_type(8)))  unsigned short u16x8;
typedef __attribute__((ext_vector_type(4)))  unsigned short u16x4;

// ---- mfma shim: gfx950 builtin may take v8bf16 or v8i16 -------------------
template <typename V>
static __device__ inline auto mfma_try(V a, V b, f32x16 c, int)
    -> decltype(__builtin_amdgcn_mfma_f32_32x32x16_bf16(a, b, c, 0, 0, 0)) {
  return __builtin_amdgcn_mfma_f32_32x32x16_bf16(a, b, c, 0, 0, 0);
}
template <typename V>
static __device__ inline f32x16 mfma_try(V a, V b, f32x16 c, long) {
  return __builtin_amdgcn_mfma_f32_32x32x16_bf16(
      __builtin_bit_cast(bf8v, a), __builtin_bit_cast(bf8v, b), c, 0, 0, 0);
}
static __device__ inline f32x16 mfma32(u16x8 a, u16x8 b, f32x16 c) {
  return mfma_try(__builtin_bit_cast(s8v, a), __builtin_bit_cast(s8v, b), c, 0);
}

// ---- bf16 split helpers ---------------------------------------------------
static __device__ inline unsigned short bf_trunc(float x) {
  return (unsigned short)(__builtin_bit_cast(unsigned int, x) >> 16);
}
static __device__ inline float bf_up(unsigned short h) {
  return __builtin_bit_cast(float, ((unsigned int)h) << 16);
}
static __device__ inline void split2(float x, unsigned short& hi, unsigned short& lo) {
  hi = bf_trunc(x);
  lo = bf_trunc(x - bf_up(hi));
}
static __device__ inline float sigmoidf_(float x) { return 1.0f / (1.0f + __expf(-x)); }
static __device__ inline float tanhf_(float x) {
  float ax = fabsf(x);
  float e  = __expf(-2.0f * ax);
  float t  = (1.0f - e) / (1.0f + e);
  return x < 0.0f ? -t : t;
}

// ---- raw memory ops (untracked by compiler; manual waitcnt discipline) ----
static __device__ inline u32x4 ld16(const void* p) {           // cached (L1/L2 ok)
  u32x4 r;
  asm volatile("global_load_dwordx4 %0, %1, off" : "=v"(r) : "v"(p) : "memory");
  return r;
}
static __device__ inline u32x4 ld_cohere16(const void* p) {    // LLC-coherent
  u32x4 r;
  asm volatile("global_load_dwordx4 %0, %1, off sc0 sc1" : "=v"(r) : "v"(p) : "memory");
  return r;
}
static __device__ inline void st_cohere2(void* p, unsigned short v) {  // write-through
  asm volatile("global_store_short %0, %1, off sc0 sc1" :: "v"(p), "v"(v) : "memory");
}
static __device__ inline void st_cohere4(void* p, int v) {
  asm volatile("global_store_dword %0, %1, off sc0 sc1" :: "v"(p), "v"(v) : "memory");
}
#define WAITVM(N)                                              \
  do {                                                         \
    asm volatile("s_waitcnt vmcnt(" #N ")" ::: "memory");      \
    __builtin_amdgcn_sched_barrier(0);                         \
  } while (0)

// ===========================================================================
// K1: embedding gather -> x split to bf16 hi/lo. row = t*32+b, 256 elems.
// ===========================================================================
__global__ void k_embed(const int* __restrict__ sent, const float* __restrict__ emb,
                        unsigned short* __restrict__ xhi, unsigned short* __restrict__ xlo) {
  int row  = blockIdx.x * 4 + (threadIdx.x >> 6);
  int lane = threadIdx.x & 63;
  int t = row >> 5, b = row & 31;
  int tok = sent[b * 256 + t];
  const f32x4v v = *(const f32x4v*)(emb + (long)tok * 256 + lane * 4);
  u16x4 h4, l4;
#pragma unroll
  for (int i = 0; i < 4; ++i) {
    unsigned short h, l;
    split2(v[i], h, l);
    h4[i] = h; l4[i] = l;
  }
  *(u16x4*)(xhi + (long)row * 256 + lane * 4) = h4;
  *(u16x4*)(xlo + (long)row * 256 + lane * 4) = l4;
}

// ===========================================================================
// K3: persistent bidirectional LSTM. 128 blocks: dir=blk>>6, b64=blk&63.
// Block owns h-indices [b64*8, b64*8+8) (32 W rows), weights live in regs as
// bf16 hi/lo MFMA B-frags. Hand-rolled release: sc0sc1 stores + vmcnt(0) +
// barrier + sc0sc1 flag store. Manual vmcnt pipeline in the hot loop.
// ===========================================================================
__global__ __launch_bounds__(256, 1) void k_lstm(
    const float* __restrict__ Whh_f, const float* __restrict__ Whh_b,
    const float* __restrict__ Wih_f, const float* __restrict__ Wih_b,
    const float* __restrict__ b_f,   const float* __restrict__ b_b,
    const float* __restrict__ h0,    const float* __restrict__ c0,
    const unsigned short* __restrict__ xhi, const unsigned short* __restrict__ xlo,
    unsigned short* __restrict__ hbhi, unsigned short* __restrict__ hblo,
    unsigned short* __restrict__ hshi, unsigned short* __restrict__ hslo,
    int* __restrict__ flags) {
  const int tid = threadIdx.x, lane = tid & 63, w = tid >> 6;
  const int blk = blockIdx.x, dir = blk >> 6, b64 = blk & 63;
  const float* Whh  = dir ? Whh_b : Whh_f;
  const float* Wih  = dir ? Wih_b : Wih_f;
  const float* bias = dir ? b_b   : b_f;

  __shared__ float zp[4][32][33];

  const int n  = lane & 31;   // B-frag col == row-list index
  const int kh = lane >> 5;   // k half within 16-wide K step
  const int wrow = ((n >> 3) << 9) + (b64 << 3) + (n & 7);  // W row (gate*512 + idx)

  // ---- preload recurrent B-frags (K=512, wave w covers [w*128, w*128+128))
  u16x8 wbh[8], wbl[8];
#pragma unroll
  for (int k8 = 0; k8 < 8; ++k8) {
    const float* src = Whh + (long)wrow * 512 + (w << 7) + (k8 << 4) + (kh << 3);
    f32x4v a = *(const f32x4v*)src, b2 = *(const f32x4v*)(src + 4);
    u16x8 hh, ll;
#pragma unroll
    for (int i = 0; i < 8; ++i) {
      float v = (i < 4) ? a[i] : b2[i - 4];
      unsigned short x1, x2; split2(v, x1, x2);
      hh[i] = x1; ll[i] = x2;
    }
    wbh[k8] = hh; wbl[k8] = ll;
  }
  // ---- preload input-proj B-frags (K=256, wave w covers [w*64, w*64+64))
  u16x8 wih_h[4], wih_l[4];
#pragma unroll
  for (int k4 = 0; k4 < 4; ++k4) {
    const float* src = Wih + (long)wrow * 256 + (w << 6) + (k4 << 4) + (kh << 3);
    f32x4v a = *(const f32x4v*)src, b2 = *(const f32x4v*)(src + 4);
    u16x8 hh, ll;
#pragma unroll
    for (int i = 0; i < 8; ++i) {
      float v = (i < 4) ? a[i] : b2[i - 4];
      unsigned short x1, x2; split2(v, x1, x2);
      hh[i] = x1; ll[i] = x2;
    }
    wih_h[k4] = hh; wih_l[k4] = ll;
  }

  // ---- gate-thread state
  const int gb = tid & 31;          // batch
  const int gi = tid >> 5;          // local h index 0..7
  const int gidx = (b64 << 3) + gi; // global h index
  float c = c0[(dir * 32 + gb) * 512 + gidx];
  float bias4[4];
#pragma unroll
  for (int g = 0; g < 4; ++g) bias4[g] = bias[(g << 9) + gidx];

  // ---- publish h_0 (parity 0): coherent stores + drain + barrier + flag
  {
    float hv = h0[(dir * 32 + gb) * 512 + gidx];
    unsigned short hh, ll; split2(hv, hh, ll);
    int off = ((0 * 2 + dir) * 64 + b64) * 256 + gb * 8 + gi;
    st_cohere2(hbhi + off, hh);
    st_cohere2(hblo + off, ll);
  }
  WAITVM(0);
  __syncthreads();
  if (tid == 0) st_cohere4(flags + dir * 64 + b64, 1);

  const int m = lane & 31;  // A-frag row == batch

  for (int step = 0; step < 256; ++step) {
    const int t = dir ? (255 - step) : step;

    // (1) issue x A-frag loads (cached; complete during flag spin)
    u32x4 xah_[4], xal_[4];
#pragma unroll
    for (int k4 = 0; k4 < 4; ++k4) {
      long ro = (long)(t * 32 + m) * 256 + (w << 6) + (k4 << 4) + (kh << 3);
      xah_[k4] = ld16(xhi + ro);
      xal_[k4] = ld16(xlo + ro);
    }

    // (2) wait for all 64 producer blocks of this direction
    {
      const int* fl = flags + dir * 64;
      const int tgt = step + 1;
      while (true) {
        int fv = __hip_atomic_load(fl + lane, __ATOMIC_RELAXED, __HIP_MEMORY_SCOPE_AGENT);
        if (__all(fv >= tgt)) break;
      }
    }

    // (3) issue h A-frag loads (LLC-coherent), parity = step&1
    const int pr = step & 1;
    const unsigned short* hb_hi = hbhi + ((pr * 2 + dir) * 64) * 256;
    const unsigned short* hb_lo = hblo + ((pr * 2 + dir) * 64) * 256;
    u32x4 ah_[8], al_[8];
#pragma unroll
    for (int k8 = 0; k8 < 8; ++k8) {
      int bs = (w << 4) + (k8 << 1) + kh;
      ah_[k8] = ld_cohere16(hb_hi + bs * 256 + m * 8);
      al_[k8] = ld_cohere16(hb_lo + bs * 256 + m * 8);
    }

    // (4) x ready once h loads in flight behind them; two acc chains for ILP
    WAITVM(16);
    f32x16 acc0 = (f32x16)0.0f, acc1 = (f32x16)0.0f;
#pragma unroll
    for (int k4 = 0; k4 < 4; ++k4) {
      u16x8 xa = __builtin_bit_cast(u16x8, xah_[k4]);
      u16x8 xl = __builtin_bit_cast(u16x8, xal_[k4]);
      if (k4 & 1) {
        acc1 = mfma32(xa, wih_h[k4], acc1);
        acc0 = mfma32(xa, wih_l[k4], acc0);
        acc1 = mfma32(xl, wih_h[k4], acc1);
      } else {
        acc0 = mfma32(xa, wih_h[k4], acc0);
        acc1 = mfma32(xa, wih_l[k4], acc1);
        acc0 = mfma32(xl, wih_h[k4], acc0);
      }
    }

    // (5) recurrent part, staged: first 8 loads (k8 0..3), then rest
    WAITVM(8);
#pragma unroll
    for (int k8 = 0; k8 < 4; ++k8) {
      u16x8 ah = __builtin_bit_cast(u16x8, ah_[k8]);
      u16x8 al = __builtin_bit_cast(u16x8, al_[k8]);
      if (k8 & 1) {
        acc1 = mfma32(ah, wbh[k8], acc1);
        acc0 = mfma32(ah, wbl[k8], acc0);
        acc1 = mfma32(al, wbh[k8], acc1);
      } else {
        acc0 = mfma32(ah, wbh[k8], acc0);
        acc1 = mfma32(ah, wbl[k8], acc1);
        acc0 = mfma32(al, wbh[k8], acc0);
      }
    }
    WAITVM(0);
#pragma unroll
    for (int k8 = 4; k8 < 8; ++k8) {
      u16x8 ah = __builtin_bit_cast(u16x8, ah_[k8]);
      u16x8 al = __builtin_bit_cast(u16x8, al_[k8]);
      if (k8 & 1) {
        acc1 = mfma32(ah, wbh[k8], acc1);
        acc0 = mfma32(ah, wbl[k8], acc0);
        acc1 = mfma32(al, wbh[k8], acc1);
      } else {
        acc0 = mfma32(ah, wbh[k8], acc0);
        acc1 = mfma32(ah, wbl[k8], acc1);
        acc0 = mfma32(al, wbh[k8], acc0);
      }
    }

    // (6) partial z to LDS: C row = (reg&3)+8*(reg>>2)+4*kh (batch), col = n
#pragma unroll
    for (int r = 0; r < 16; ++r) {
      int mr = (r & 3) + ((r >> 2) << 3) + (kh << 2);
      zp[w][mr][n] = acc0[r] + acc1[r];
    }
    __syncthreads();

    // (7) gate math
    float z[4];
#pragma unroll
    for (int g = 0; g < 4; ++g)
      z[g] = zp[0][gb][g * 8 + gi] + zp[1][gb][g * 8 + gi] +
             zp[2][gb][g * 8 + gi] + zp[3][gb][g * 8 + gi] + bias4[g];
    float ig = sigmoidf_(z[0]);
    float fg = sigmoidf_(z[1]);
    float gg = tanhf_(z[2]);
    float og = sigmoidf_(z[3]);
    c = fg * c + ig * gg;
    float nh = og * tanhf_(c);

    // (8) publish h: coherent stores, drain, barrier, flag
    unsigned short hh, ll; split2(nh, hh, ll);
    const int pw = (step + 1) & 1;
    int off = ((pw * 2 + dir) * 64 + b64) * 256 + gb * 8 + gi;
    st_cohere2(hbhi + off, hh);
    st_cohere2(hblo + off, ll);
    long ho = ((long)(dir * 256 + t) * 64 + b64) * 256 + gb * 8 + gi;
    hshi[ho] = hh; hslo[ho] = ll;  // history: plain cached (read next kernel)

    WAITVM(0);
    __syncthreads();
    if (tid == 0) st_cohere4(flags + dir * 64 + b64, step + 2);
  }
}

// ===========================================================================
// K4: feats[b,t,k] = concat(hf,hb) @ Wout^T + bout. One block per t.
// ===========================================================================
__global__ __launch_bounds__(256, 1) void k_feats(
    const unsigned short* __restrict__ hshi, const unsigned short* __restrict__ hslo,
    const float* __restrict__ Wout, const float* __restrict__ bout,
    float* __restrict__ feats) {
  const int tid = threadIdx.x, lane = tid & 63, w = tid >> 6;
  const int t = blockIdx.x;
  __shared__ float zp[4][32][33];
  const int n = lane & 31, kh = lane >> 5;
  const int dirw = w >> 1, koff = (w & 1) * 256;

  u16x8 bh[16], bl[16];
#pragma unroll
  for (int k = 0; k < 16; ++k) {
    const float* src = Wout + (long)n * 1024 + dirw * 512 + koff + (k << 4) + (kh << 3);
    f32x4v a = *(const f32x4v*)src, b2 = *(const f32x4v*)(src + 4);
    u16x8 hh, ll;
#pragma unroll
    for (int i = 0; i < 8; ++i) {
      float v = (i < 4) ? a[i] : b2[i - 4];
      unsigned short x1, x2; split2(v, x1, x2);
      hh[i] = x1; ll[i] = x2;
    }
    bh[k] = hh; bl[k] = ll;
  }

  const int m = lane & 31;  // batch
  f32x16 acc = (f32x16)0.0f;
  const unsigned short* base_h = hshi + ((long)(dirw * 256 + t) * 64) * 256;
  const unsigned short* base_l = hslo + ((long)(dirw * 256 + t) * 64) * 256;
#pragma unroll
  for (int k = 0; k < 16; ++k) {
    int ksrc = koff + (k << 4) + (kh << 3);
    int bs = ksrc >> 3;
    u16x8 ah = *(const u16x8*)(base_h + bs * 256 + m * 8);
    u16x8 al = *(const u16x8*)(base_l + bs * 256 + m * 8);
    acc = mfma32(ah, bh[k], acc);
    acc = mfma32(ah, bl[k], acc);
    acc = mfma32(al, bh[k], acc);
  }
#pragma unroll
  for (int r = 0; r < 16; ++r) {
    int mr = (r & 3) + ((r >> 2) << 3) + (kh << 2);
    zp[w][mr][n] = acc[r];
  }
  __syncthreads();

  const int k = tid & 31, mb = tid >> 5;
#pragma unroll
  for (int q = 0; q < 4; ++q) {
    int mm = mb * 4 + q;  // batch
    float v = zp[0][mm][k] + zp[1][mm][k] + zp[2][mm][k] + zp[3][mm][k] + bout[k];
    feats[((long)mm * 256 + t) * 32 + k] = v;
  }
}

// ===========================================================================
// K5: Viterbi. One wave per batch, barrier-free scan: trans row in registers
// (statically indexed), feats staged in LDS, vl exchanged via shfl.
// ===========================================================================
__global__ __launch_bounds__(64, 1) void k_viterbi(const float* __restrict__ feats,
                                                   const float* __restrict__ trans,
                                                   float* __restrict__ out) {
  const int b = blockIdx.x, lane = threadIdx.x;
  __shared__ __align__(16) float fsh[256][32];
  __shared__ unsigned char bp[256][32];

  const float* fb = feats + (long)b * 8192;
#pragma unroll 4
  for (int i = lane; i < 2048; i += 64)
    ((f32x4v*)&fsh[0][0])[i] = ((const f32x4v*)fb)[i];

  float tr_[32];
  float vl = 0.0f;
  if (lane < 32) {
#pragma unroll
    for (int p = 0; p < 32; ++p) tr_[p] = trans[lane * 32 + p];
    vl = (lane == 30) ? 0.0f : -10000.0f;
  }
  __syncthreads();

  if (lane < 32) {
    for (int t = 0; t < 256; ++t) {
      float best = -3.0e38f; int arg = 0;
#pragma unroll
      for (int p = 0; p < 32; ++p) {
        float vp = __shfl(vl, p, 32);
        float sc = vp + tr_[p];
        if (sc > best) { best = sc; arg = p; }  // strict > keeps FIRST max
      }
      vl = best + fsh[t][lane];
      bp[t][lane] = (unsigned char)arg;
    }
    // terminal = v + trans[STOP=31][:], argmax with first-index tie-break
    float tv = vl + trans[31 * 32 + lane];
    int ta = lane;
#pragma unroll
    for (int d = 16; d; d >>= 1) {
      float ov = __shfl_xor(tv, d, 32);
      int   oa = __shfl_xor(ta, d, 32);
      if (ov > tv || (ov == tv && oa < ta)) { tv = ov; ta = oa; }
    }
    if (lane == 0) {
      out[b] = tv;
      int tag = ta;
      for (int t = 255; t >= 0; --t) {
        out[32 + (long)b * 256 + t] = (float)tag;
        tag = bp[t][tag];
      }
    }
  }
}

// ===========================================================================
extern "C" void kernel_launch(void* const* d_in, const int* in_sizes, int n_in,
                              void* d_out, int out_size, void* d_ws, size_t ws_size,
                              hipStream_t stream) {
  (void)in_sizes; (void)n_in; (void)out_size; (void)ws_size;
  const int*   sent  = (const int*)d_in[0];
  const float* emb   = (const float*)d_in[1];
  const float* Wih_f = (const float*)d_in[2];
  const float* Whh_f = (const float*)d_in[3];
  const float* b_f   = (const float*)d_in[4];
  const float* Wih_b = (const float*)d_in[5];
  const float* Whh_b = (const float*)d_in[6];
  const float* b_b   = (const float*)d_in[7];
  const float* Wout  = (const float*)d_in[8];
  const float* bout  = (const float*)d_in[9];
  const float* trans = (const float*)d_in[10];
  const float* h0    = (const float*)d_in[11];
  const float* c0    = (const float*)d_in[12];
  float* out = (float*)d_out;

  char* ws = (char*)d_ws;
  unsigned short* xhi  = (unsigned short*)(ws + 0);                       // 4 MB
  unsigned short* xlo  = (unsigned short*)(ws + (4ull << 20));            // 4 MB
  unsigned short* hbhi = (unsigned short*)(ws + (8ull << 20));            // 128 KB
  unsigned short* hblo = (unsigned short*)(ws + (8ull << 20) + (256ull << 10));
  unsigned short* hshi = (unsigned short*)(ws + (9ull << 20));            // 16 MB
  unsigned short* hslo = (unsigned short*)(ws + (26ull << 20));           // 16 MB
  float*          fts  = (float*)(ws + (43ull << 20));                    // 1 MB
  int*            flg  = (int*)(ws + (45ull << 20));                      // 512 B

  hipMemsetAsync(flg, 0, 128 * sizeof(int), stream);
  k_embed<<<2048, 256, 0, stream>>>(sent, emb, xhi, xlo);
  k_lstm<<<128, 256, 0, stream>>>(Whh_f, Whh_b, Wih_f, Wih_b, b_f, b_b, h0, c0,
                                  xhi, xlo, hbhi, hblo, hshi, hslo, flg);
  k_feats<<<256, 256, 0, stream>>>(hshi, hslo, Wout, bout, fts);
  k_viterbi<<<32, 64, 0, stream>>>(fts, trans, out);
}